// Round 1
// baseline (662.869 us; speedup 1.0000x reference)
//
#include <hip/hip_runtime.h>
#include <math.h>

#define B_ 32
#define S_ 2048
#define D_ 512
#define H_ 512

typedef __bf16 bf16x8 __attribute__((ext_vector_type(8)));
typedef float f32x4 __attribute__((ext_vector_type(4)));
typedef short short4v __attribute__((ext_vector_type(4)));
typedef short short8v __attribute__((ext_vector_type(8)));

__device__ __forceinline__ unsigned short f2bf(float f) {
  unsigned u = __float_as_uint(f);
  u += 0x7fffu + ((u >> 16) & 1u);
  return (unsigned short)(u >> 16);
}
__device__ __forceinline__ float bf2f(unsigned short s) {
  return __uint_as_float(((unsigned)s) << 16);
}

// inp[b,h] = bi[h] + sum_k x[b,k] * Wi[h,k]
__global__ __launch_bounds__(256) void prep_inp_k(const float* __restrict__ x,
    const float* __restrict__ Wi, const float* __restrict__ bi, float* __restrict__ inp) {
  int gid = blockIdx.x * 256 + threadIdx.x;   // 16384
  int b = gid >> 9, h = gid & 511;
  const float* xr = x + b * 512;
  const float* wr = Wi + h * 512;
  float acc = bi[h];
  #pragma unroll 4
  for (int k = 0; k < 512; k += 4) {
    float4 xv = *(const float4*)(xr + k);
    float4 wv = *(const float4*)(wr + k);
    acc += xv.x * wv.x + xv.y * wv.y + xv.z * wv.z + xv.w * wv.w;
  }
  inp[gid] = acc;
}

// Wcat[n,k] (n = g*512+h) split into bf16 hi/lo
__global__ __launch_bounds__(256) void prep_w_k(const float* __restrict__ w0,
    const float* __restrict__ w1, const float* __restrict__ w2, const float* __restrict__ w3,
    short* __restrict__ Whi, short* __restrict__ Wlo) {
  int gid = blockIdx.x * 256 + threadIdx.x;   // 262144 quads
  int n = gid >> 7, q = gid & 127;
  int k = q * 4;
  int g = n >> 9, h = n & 511;
  const float* w = (g == 0) ? w0 : (g == 1) ? w1 : (g == 2) ? w2 : w3;
  float4 v = *(const float4*)(w + h * 512 + k);
  unsigned short a0 = f2bf(v.x), a1 = f2bf(v.y), a2 = f2bf(v.z), a3 = f2bf(v.w);
  short4v hv = { (short)a0, (short)a1, (short)a2, (short)a3 };
  short4v lv = { (short)f2bf(v.x - bf2f(a0)), (short)f2bf(v.y - bf2f(a1)),
                 (short)f2bf(v.z - bf2f(a2)), (short)f2bf(v.w - bf2f(a3)) };
  *(short4v*)(Whi + (size_t)n * 512 + k) = hv;
  *(short4v*)(Wlo + (size_t)n * 512 + k) = lv;
}

// Main GEMM + fused tanh/V-reduce epilogue.
// Grid: (nt=16, mt=16, b=32); block 256 (4 waves, 2x2 over 128x128 tile).
__global__ __launch_bounds__(256) void main_gemm_k(
    const float* __restrict__ ctx, const short* __restrict__ Whi, const short* __restrict__ Wlo,
    const float* __restrict__ inp,
    const float* __restrict__ bc0, const float* __restrict__ bc1,
    const float* __restrict__ bc2, const float* __restrict__ bc3,
    const float* __restrict__ V, float* __restrict__ att) {
  __shared__ short Ah[128][40];   // stride 40 shorts = 80B: 16B-aligned rows, ~2-way banks
  __shared__ short Al[128][40];
  __shared__ short Bh[128][40];
  __shared__ short Bl[128][40];
  __shared__ float sV[128], sBC[128], sInp[128];

  const int t = threadIdx.x;
  const int nt = blockIdx.x, mt = blockIdx.y, b = blockIdx.z;
  const int n0 = nt * 128, s0 = mt * 128;
  const int g = n0 >> 9, h0 = n0 & 511;

  if (t < 128) {
    sV[t] = V[h0 + t];
    const float* bc = (g == 0) ? bc0 : (g == 1) ? bc1 : (g == 2) ? bc2 : bc3;
    sBC[t] = bc[h0 + t];
    sInp[t] = inp[b * 512 + h0 + t];
  }

  f32x4 acc[4][4];
  #pragma unroll
  for (int i = 0; i < 4; ++i)
    #pragma unroll
    for (int j = 0; j < 4; ++j) acc[i][j] = (f32x4){0.f, 0.f, 0.f, 0.f};

  const float* ctxB = ctx + ((size_t)b * S_ + s0) * D_;
  const short* WhiB = Whi + (size_t)n0 * D_;
  const short* WloB = Wlo + (size_t)n0 * D_;
  const int lane = t & 63, wid = t >> 6;
  const int wy = wid >> 1, wx = wid & 1;
  const int fr = lane & 15, fq = lane >> 4;

  for (int kt = 0; kt < 512; kt += 32) {
    // stage A tile [128 s][32 k]: fp32 -> bf16 hi/lo
    #pragma unroll
    for (int i = 0; i < 4; ++i) {
      int fi = t + i * 256;
      int row = fi >> 3, c4 = (fi & 7) * 4;
      float4 v = *(const float4*)(ctxB + row * 512 + kt + c4);
      unsigned short a0 = f2bf(v.x), a1 = f2bf(v.y), a2 = f2bf(v.z), a3 = f2bf(v.w);
      short4v hv = { (short)a0, (short)a1, (short)a2, (short)a3 };
      short4v lv = { (short)f2bf(v.x - bf2f(a0)), (short)f2bf(v.y - bf2f(a1)),
                     (short)f2bf(v.z - bf2f(a2)), (short)f2bf(v.w - bf2f(a3)) };
      *(short4v*)&Ah[row][c4] = hv;
      *(short4v*)&Al[row][c4] = lv;
    }
    // stage B tile [128 n][32 k] from pre-split bf16
    #pragma unroll
    for (int i = 0; i < 2; ++i) {
      int ci = t + i * 256;
      int row = ci >> 2, q = (ci & 3) * 8;
      short8v hv = *(const short8v*)(WhiB + row * 512 + kt + q);
      short8v lv = *(const short8v*)(WloB + row * 512 + kt + q);
      *(short8v*)&Bh[row][q] = hv;
      *(short8v*)&Bl[row][q] = lv;
    }
    __syncthreads();

    bf16x8 ah[4], al[4], bh[4], bl[4];
    #pragma unroll
    for (int i = 0; i < 4; ++i) {
      ah[i] = *(const bf16x8*)&Ah[wy * 64 + i * 16 + fr][fq * 8];
      al[i] = *(const bf16x8*)&Al[wy * 64 + i * 16 + fr][fq * 8];
      bh[i] = *(const bf16x8*)&Bh[wx * 64 + i * 16 + fr][fq * 8];
      bl[i] = *(const bf16x8*)&Bl[wx * 64 + i * 16 + fr][fq * 8];
    }
    #pragma unroll
    for (int mi = 0; mi < 4; ++mi)
      #pragma unroll
      for (int ni = 0; ni < 4; ++ni) {
        acc[mi][ni] = __builtin_amdgcn_mfma_f32_16x16x32_bf16(ah[mi], bh[ni], acc[mi][ni], 0, 0, 0);
        acc[mi][ni] = __builtin_amdgcn_mfma_f32_16x16x32_bf16(ah[mi], bl[ni], acc[mi][ni], 0, 0, 0);
        acc[mi][ni] = __builtin_amdgcn_mfma_f32_16x16x32_bf16(al[mi], bh[ni], acc[mi][ni], 0, 0, 0);
      }
    __syncthreads();
  }

  // epilogue: att[b, g*2048 + s] += sum_n V[h] * tanh(inp + bc + Y)
  #pragma unroll
  for (int mi = 0; mi < 4; ++mi) {
    #pragma unroll
    for (int r = 0; r < 4; ++r) {
      float sum = 0.f;
      #pragma unroll
      for (int ni = 0; ni < 4; ++ni) {
        int hl = wx * 64 + ni * 16 + fr;
        float y = acc[mi][ni][r];
        sum += sV[hl] * tanhf(sInp[hl] + sBC[hl] + y);
      }
      #pragma unroll
      for (int m = 1; m < 16; m <<= 1) sum += __shfl_xor(sum, m, 64);
      if (fr == 0) {
        int s = s0 + wy * 64 + mi * 16 + fq * 4 + r;
        atomicAdd(&att[(size_t)b * 8192 + g * 2048 + s], sum);
      }
    }
  }
}

// Per-batch argmax (first-index ties, numpy semantics) + softmax max + mask out
__global__ __launch_bounds__(256) void finalize_k(const float* __restrict__ att,
    const unsigned char* __restrict__ mask, float* __restrict__ out) {
  int b = blockIdx.x, t = threadIdx.x;
  __shared__ float smax[256];
  __shared__ int sidx[256];
  __shared__ float ssum[256];
  float bm = -1e30f;
  int bidx = 0x7fffffff;
  for (int j = t; j < 8192; j += 256) {
    if (mask[b * 2048 + (j & 2047)]) continue;
    float a = att[(size_t)b * 8192 + j];   // 10*tanh is monotone; argmax on raw
    if (a > bm) { bm = a; bidx = j; }      // strict > keeps first index per thread
  }
  smax[t] = bm; sidx[t] = bidx;
  __syncthreads();
  for (int s2 = 128; s2 > 0; s2 >>= 1) {
    if (t < s2) {
      float o = smax[t + s2]; int oi = sidx[t + s2];
      if (o > smax[t] || (o == smax[t] && oi < sidx[t])) { smax[t] = o; sidx[t] = oi; }
    }
    __syncthreads();
  }
  float amax10 = 10.f * tanhf(smax[0]);
  float se = 0.f;
  for (int j = t; j < 8192; j += 256) {
    if (mask[b * 2048 + (j & 2047)]) continue;
    se += expf(10.f * tanhf(att[(size_t)b * 8192 + j]) - amax10);
  }
  ssum[t] = se;
  __syncthreads();
  for (int s2 = 128; s2 > 0; s2 >>= 1) {
    if (t < s2) ssum[t] += ssum[t + s2];
    __syncthreads();
  }
  if (t == 0) {
    out[b] = (float)sidx[0];        // indices [B,1]
    out[32 + b] = 1.f / ssum[0];    // p [B,1]
  }
  for (int j = t; j < 2048; j += 256)
    out[64 + b * 2048 + j] = mask[b * 2048 + j] ? 1.0f : 0.0f;   // mask passthrough
}

extern "C" void kernel_launch(void* const* d_in, const int* in_sizes, int n_in,
                              void* d_out, int out_size, void* d_ws, size_t ws_size,
                              hipStream_t stream) {
  const float* x    = (const float*)d_in[0];
  const float* ctx  = (const float*)d_in[1];
  const unsigned char* mask = (const unsigned char*)d_in[2];
  const float* Wi   = (const float*)d_in[3];
  const float* bi   = (const float*)d_in[4];
  const float* Wc0  = (const float*)d_in[5];
  const float* bc0  = (const float*)d_in[6];
  const float* Wc1  = (const float*)d_in[7];
  const float* bc1  = (const float*)d_in[8];
  const float* Wc2  = (const float*)d_in[9];
  const float* bc2  = (const float*)d_in[10];
  const float* Wc3  = (const float*)d_in[11];
  const float* bc3  = (const float*)d_in[12];
  const float* V    = (const float*)d_in[13];
  float* out = (float*)d_out;

  // ws layout: inp[32*512] f32 | att[32*8192] f32 | Whi[2048*512] bf16 | Wlo[...]
  float* inp = (float*)d_ws;
  float* att = inp + 16384;
  short* Whi = (short*)(att + 262144);
  short* Wlo = Whi + (size_t)2048 * 512;

  hipMemsetAsync(att, 0, 262144 * sizeof(float), stream);
  prep_inp_k<<<64, 256, 0, stream>>>(x, Wi, bi, inp);
  prep_w_k<<<1024, 256, 0, stream>>>(Wc0, Wc1, Wc2, Wc3, Whi, Wlo);
  main_gemm_k<<<dim3(16, 16, 32), 256, 0, stream>>>(ctx, Whi, Wlo, inp,
                                                    bc0, bc1, bc2, bc3, V, att);
  finalize_k<<<32, 256, 0, stream>>>(att, mask, out);
}

// Round 3
// 466.473 us; speedup vs baseline: 1.4210x; 1.4210x over previous
//
#include <hip/hip_runtime.h>
#include <math.h>

typedef __bf16 bf16x8 __attribute__((ext_vector_type(8)));
typedef float f32x4 __attribute__((ext_vector_type(4)));
typedef short short8v __attribute__((ext_vector_type(8)));

__device__ __forceinline__ unsigned short f2bf(float f) {
  unsigned u = __float_as_uint(f);
  u += 0x7fffu + ((u >> 16) & 1u);
  return (unsigned short)(u >> 16);
}
__device__ __forceinline__ float bf2f(unsigned short s) {
  return __uint_as_float(((unsigned)s) << 16);
}
__device__ __forceinline__ void split8(const float* f, short8v& h, short8v& l) {
  #pragma unroll
  for (int i = 0; i < 8; ++i) {
    unsigned short a = f2bf(f[i]);
    h[i] = (short)a;
    l[i] = (short)f2bf(f[i] - bf2f(a));
  }
}
__device__ __forceinline__ float tanh_fast(float x) {
  // tanh(x) = 1 - 2/(exp(2x)+1); exp2-based, ~1ulp rcp — plenty for att
  float e = __builtin_amdgcn_exp2f(x * 2.885390081777927f);
  return 1.f - 2.f * __builtin_amdgcn_rcpf(e + 1.f);
}
__device__ __forceinline__ void gl_lds16(const void* g, void* l) {
  __builtin_amdgcn_global_load_lds(
      (const __attribute__((address_space(1))) unsigned int*)g,
      (__attribute__((address_space(3))) unsigned int*)l, 16, 0, 0);
}

// inp[b,h] = bi[h] + sum_k x[b,k] * Wi[h,k]
__global__ __launch_bounds__(256) void prep_inp_k(const float* __restrict__ x,
    const float* __restrict__ Wi, const float* __restrict__ bi, float* __restrict__ inp) {
  int gid = blockIdx.x * 256 + threadIdx.x;   // 16384
  int b = gid >> 9, h = gid & 511;
  const float* xr = x + b * 512;
  const float* wr = Wi + h * 512;
  float acc = bi[h];
  #pragma unroll 4
  for (int k = 0; k < 512; k += 4) {
    float4 xv = *(const float4*)(xr + k);
    float4 wv = *(const float4*)(wr + k);
    acc += xv.x * wv.x + xv.y * wv.y + xv.z * wv.z + xv.w * wv.w;
  }
  inp[gid] = acc;
}

// W packed: region (TN in 0..7, KS in 0..15) = 256 n-rows x 32 k, row-major
// [row][k], split hi/lo. Region linear = ((TN*16+KS)*256+row)*32 + c*8.
// Total chunks = 2048*512/8 = 131072 -> grid 512 x 256.
__global__ __launch_bounds__(256) void prep_w_pack_k(const float* __restrict__ w0,
    const float* __restrict__ w1, const float* __restrict__ w2, const float* __restrict__ w3,
    short* __restrict__ Whi, short* __restrict__ Wlo) {
  int gid = blockIdx.x * 256 + threadIdx.x;
  if (gid >= 131072) return;                  // guard (bug fix R2: grid was 4x over)
  int c = gid & 3, row = (gid >> 2) & 255, TK = gid >> 10;  // TK = TN*16+KS, 0..127
  int TN = TK >> 4, KS = TK & 15;
  int n = TN * 256 + row;
  int g = n >> 9, h = n & 511;
  const float* w = (g == 0) ? w0 : (g == 1) ? w1 : (g == 2) ? w2 : w3;
  float f[8];
  *(float4*)&f[0] = *(const float4*)(w + (size_t)h * 512 + KS * 32 + c * 8);
  *(float4*)&f[4] = *(const float4*)(w + (size_t)h * 512 + KS * 32 + c * 8 + 4);
  short8v hv, lv;
  split8(f, hv, lv);
  *(short8v*)(Whi + (size_t)gid * 8) = hv;
  *(short8v*)(Wlo + (size_t)gid * 8) = lv;
}

// ctx packed: region (TM in 0..255, KS in 0..15) = 256 m-rows x 32 k.
__global__ __launch_bounds__(256) void prep_ctx_pack_k(const float* __restrict__ ctx,
    short* __restrict__ Chi, short* __restrict__ Clo) {
  int gid = blockIdx.x * 256 + threadIdx.x;   // 4194304 chunks of 8
  int c = gid & 3, row = (gid >> 2) & 255, TK = gid >> 10;  // TK = TM*16+KS
  int TM = TK >> 4, KS = TK & 15;
  size_t m = (size_t)TM * 256 + row;
  int k = KS * 32 + c * 8;
  float f[8];
  *(float4*)&f[0] = *(const float4*)(ctx + m * 512 + k);
  *(float4*)&f[4] = *(const float4*)(ctx + m * 512 + k + 4);
  short8v hv, lv;
  split8(f, hv, lv);
  *(short8v*)(Chi + (size_t)gid * 8) = hv;
  *(short8v*)(Clo + (size_t)gid * 8) = lv;
}

// Main: 256x256 tile, BK=32, 8 waves (2 wr x 4 wc), per-wave 128x64.
// 3-term split-bf16 MFMA (AhBh + AhBl + AlBh). Fused tanh/V epilogue -> att.
template<bool PRESPLIT>
__global__ __launch_bounds__(512, 2) void gemm_att_k(
    const float* __restrict__ ctx,
    const short* __restrict__ Chi, const short* __restrict__ Clo,
    const short* __restrict__ Whi, const short* __restrict__ Wlo,
    const float* __restrict__ inp,
    const float* __restrict__ bc0, const float* __restrict__ bc1,
    const float* __restrict__ bc2, const float* __restrict__ bc3,
    const float* __restrict__ V, float* __restrict__ att) {
  // [buf][0]=Ah [1]=Al [2]=Bh [3]=Bl, each 256 rows x 32 k (64B rows, linear)
  __shared__ __align__(16) short smem[2][4][8192];   // 128 KiB
  __shared__ float sV[256], sPre[256];

  const int t = threadIdx.x;
  int d = blockIdx.x + (blockIdx.y << 3);        // dispatch-linear 0..2047
  int work = (d & 7) * 256 + (d >> 3);           // XCD-contiguous chunks
  int mt = work >> 3, nt = work & 7;             // mt: 256-row strip, nt: 256-col
  int b = mt >> 3;                               // 2048 rows per batch
  int g = nt >> 1, h0 = (nt & 1) * 256;

  if (t < 256) {
    const float* bc = (g == 0) ? bc0 : (g == 1) ? bc1 : (g == 2) ? bc2 : bc3;
    sV[t] = V[h0 + t];
    sPre[t] = inp[b * 512 + h0 + t] + bc[h0 + t];
  }

  const int toff = t * 8;   // shorts; = t*16 bytes -> wave-uniform base + lane*16
  auto stage = [&](int buf, int ks) {
    short* lb = &smem[buf][0][0];
    if (PRESPLIT) {
      const short* gAh = Chi + (((size_t)mt * 16 + ks) << 13) + toff;
      const short* gAl = Clo + (((size_t)mt * 16 + ks) << 13) + toff;
      gl_lds16(gAh,        lb + toff);
      gl_lds16(gAh + 4096, lb + toff + 4096);
      gl_lds16(gAl,        lb + 8192 + toff);
      gl_lds16(gAl + 4096, lb + 8192 + toff + 4096);
    } else {
      int row = t >> 1, half = t & 1;
      const float* src = ctx + ((size_t)mt * 256 + row) * 512 + ks * 32 + half * 16;
      float f0[8], f1[8];
      *(float4*)&f0[0] = *(const float4*)(src);
      *(float4*)&f0[4] = *(const float4*)(src + 4);
      *(float4*)&f1[0] = *(const float4*)(src + 8);
      *(float4*)&f1[4] = *(const float4*)(src + 12);
      short8v h0v, l0v, h1v, l1v;
      split8(f0, h0v, l0v);
      split8(f1, h1v, l1v);
      int o = row * 32 + half * 16;
      *(short8v*)&smem[buf][0][o] = h0v;
      *(short8v*)&smem[buf][0][o + 8] = h1v;
      *(short8v*)&smem[buf][1][o] = l0v;
      *(short8v*)&smem[buf][1][o + 8] = l1v;
    }
    const short* gBh = Whi + (((size_t)nt * 16 + ks) << 13) + toff;
    const short* gBl = Wlo + (((size_t)nt * 16 + ks) << 13) + toff;
    gl_lds16(gBh,        lb + 16384 + toff);
    gl_lds16(gBh + 4096, lb + 16384 + toff + 4096);
    gl_lds16(gBl,        lb + 24576 + toff);
    gl_lds16(gBl + 4096, lb + 24576 + toff + 4096);
  };

  f32x4 acc[8][4];
  #pragma unroll
  for (int i = 0; i < 8; ++i)
    #pragma unroll
    for (int j = 0; j < 4; ++j) acc[i][j] = (f32x4){0.f, 0.f, 0.f, 0.f};

  const int lane = t & 63, wid = t >> 6;
  const int wr = wid >> 2, wc = wid & 3;
  const int fr = lane & 15, fq = lane >> 4;

  stage(0, 0);
  __syncthreads();

  for (int ks = 0; ks < 16; ++ks) {
    int cur = ks & 1;
    if (ks + 1 < 16) stage(cur ^ 1, ks + 1);

    const short* sa = &smem[cur][0][0];
    bf16x8 ah[8], al[8], bh[4], bl[4];
    #pragma unroll
    for (int mi = 0; mi < 8; ++mi) {
      int r = (wr * 128 + mi * 16 + fr) * 32 + fq * 8;
      ah[mi] = *(const bf16x8*)(sa + r);
      al[mi] = *(const bf16x8*)(sa + 8192 + r);
    }
    #pragma unroll
    for (int ni = 0; ni < 4; ++ni) {
      int r = (wc * 64 + ni * 16 + fr) * 32 + fq * 8;
      bh[ni] = *(const bf16x8*)(sa + 16384 + r);
      bl[ni] = *(const bf16x8*)(sa + 24576 + r);
    }
    #pragma unroll
    for (int mi = 0; mi < 8; ++mi)
      #pragma unroll
      for (int ni = 0; ni < 4; ++ni) {
        acc[mi][ni] = __builtin_amdgcn_mfma_f32_16x16x32_bf16(ah[mi], bh[ni], acc[mi][ni], 0, 0, 0);
        acc[mi][ni] = __builtin_amdgcn_mfma_f32_16x16x32_bf16(ah[mi], bl[ni], acc[mi][ni], 0, 0, 0);
        acc[mi][ni] = __builtin_amdgcn_mfma_f32_16x16x32_bf16(al[mi], bh[ni], acc[mi][ni], 0, 0, 0);
      }
    __syncthreads();
  }

  // epilogue: att[b, g*2048 + s] += sum_n V[h]*tanh(pre[h] + Y[n,s])
  float vV[4], vP[4];
  #pragma unroll
  for (int ni = 0; ni < 4; ++ni) {
    int j = wc * 64 + ni * 16 + fr;
    vV[ni] = sV[j];
    vP[ni] = sPre[j];
  }
  size_t abase = (size_t)b * 8192 + (size_t)g * 2048;
  #pragma unroll
  for (int mi = 0; mi < 8; ++mi) {
    #pragma unroll
    for (int r = 0; r < 4; ++r) {
      float sum = 0.f;
      #pragma unroll
      for (int ni = 0; ni < 4; ++ni)
        sum += vV[ni] * tanh_fast(vP[ni] + acc[mi][ni][r]);
      sum += __shfl_xor(sum, 1, 64);
      sum += __shfl_xor(sum, 2, 64);
      sum += __shfl_xor(sum, 4, 64);
      sum += __shfl_xor(sum, 8, 64);
      if (fr == 0) {
        int s = (mt * 256 + wr * 128 + mi * 16 + fq * 4 + r) & 2047;
        atomicAdd(&att[abase + s], sum);
      }
    }
  }
}

// Per-batch argmax (first-index ties) + softmax max prob + mask passthrough
__global__ __launch_bounds__(256) void finalize_k(const float* __restrict__ att,
    const unsigned char* __restrict__ mask, float* __restrict__ out) {
  int b = blockIdx.x, t = threadIdx.x;
  __shared__ float smax[256];
  __shared__ int sidx[256];
  __shared__ float ssum[256];
  float bm = -1e30f;
  int bidx = 0x7fffffff;
  for (int j = t; j < 8192; j += 256) {
    if (mask[b * 2048 + (j & 2047)]) continue;
    float a = att[(size_t)b * 8192 + j];   // 10*tanh monotone; argmax on raw
    if (a > bm) { bm = a; bidx = j; }
  }
  smax[t] = bm; sidx[t] = bidx;
  __syncthreads();
  for (int s2 = 128; s2 > 0; s2 >>= 1) {
    if (t < s2) {
      float o = smax[t + s2]; int oi = sidx[t + s2];
      if (o > smax[t] || (o == smax[t] && oi < sidx[t])) { smax[t] = o; sidx[t] = oi; }
    }
    __syncthreads();
  }
  float amax10 = 10.f * tanhf(smax[0]);
  float se = 0.f;
  for (int j = t; j < 8192; j += 256) {
    if (mask[b * 2048 + (j & 2047)]) continue;
    se += expf(10.f * tanhf(att[(size_t)b * 8192 + j]) - amax10);
  }
  ssum[t] = se;
  __syncthreads();
  for (int s2 = 128; s2 > 0; s2 >>= 1) {
    if (t < s2) ssum[t] += ssum[t + s2];
    __syncthreads();
  }
  if (t == 0) {
    out[b] = (float)sidx[0];
    out[32 + b] = 1.f / ssum[0];
  }
  for (int j = t; j < 2048; j += 256)
    out[64 + b * 2048 + j] = mask[b * 2048 + j] ? 1.0f : 0.0f;
}

extern "C" void kernel_launch(void* const* d_in, const int* in_sizes, int n_in,
                              void* d_out, int out_size, void* d_ws, size_t ws_size,
                              hipStream_t stream) {
  const float* x    = (const float*)d_in[0];
  const float* ctx  = (const float*)d_in[1];
  const unsigned char* mask = (const unsigned char*)d_in[2];
  const float* Wi   = (const float*)d_in[3];
  const float* bi   = (const float*)d_in[4];
  const float* Wc0  = (const float*)d_in[5];
  const float* bc0  = (const float*)d_in[6];
  const float* Wc1  = (const float*)d_in[7];
  const float* bc1  = (const float*)d_in[8];
  const float* Wc2  = (const float*)d_in[9];
  const float* bc2  = (const float*)d_in[10];
  const float* Wc3  = (const float*)d_in[11];
  const float* bc3  = (const float*)d_in[12];
  const float* V    = (const float*)d_in[13];
  float* out = (float*)d_out;

  // ws: inp 64KB | att 1MB | Whi 2MB | Wlo 2MB | Chi 64MB | Clo 64MB
  float* inp = (float*)d_ws;
  float* att = inp + 16384;
  short* Whi = (short*)(att + 262144);
  short* Wlo = Whi + (size_t)1048576;
  short* Chi = Wlo + (size_t)1048576;
  short* Clo = Chi + (size_t)33554432;
  size_t need = (size_t)((char*)(Clo + 33554432) - (char*)d_ws);
  bool presplit = ws_size >= need;

  hipMemsetAsync(att, 0, 262144 * sizeof(float), stream);
  prep_inp_k<<<64, 256, 0, stream>>>(x, Wi, bi, inp);
  prep_w_pack_k<<<512, 256, 0, stream>>>(Wc0, Wc1, Wc2, Wc3, Whi, Wlo);
  if (presplit) {
    prep_ctx_pack_k<<<16384, 256, 0, stream>>>(ctx, Chi, Clo);
    gemm_att_k<true><<<dim3(8, 256), 512, 0, stream>>>(ctx, Chi, Clo, Whi, Wlo,
        inp, bc0, bc1, bc2, bc3, V, att);
  } else {
    gemm_att_k<false><<<dim3(8, 256), 512, 0, stream>>>(ctx, nullptr, nullptr, Whi, Wlo,
        inp, bc0, bc1, bc2, bc3, V, att);
  }
  finalize_k<<<32, 256, 0, stream>>>(att, mask, out);
}

// Round 4
// 389.287 us; speedup vs baseline: 1.7028x; 1.1983x over previous
//
#include <hip/hip_runtime.h>
#include <math.h>

typedef __bf16 bf16x8 __attribute__((ext_vector_type(8)));
typedef float f32x4 __attribute__((ext_vector_type(4)));
typedef short short8v __attribute__((ext_vector_type(8)));

#define MARGIN 0.01f
#define NCAND 32

__device__ __forceinline__ unsigned short f2bf(float f) {
  unsigned u = __float_as_uint(f);
  u += 0x7fffu + ((u >> 16) & 1u);
  return (unsigned short)(u >> 16);
}
__device__ __forceinline__ float tanh_fast(float x) {
  float e = __builtin_amdgcn_exp2f(x * 2.885390081777927f);
  return 1.f - 2.f * __builtin_amdgcn_rcpf(e + 1.f);
}
__device__ __forceinline__ void gl_lds16(const void* g, void* l) {
  __builtin_amdgcn_global_load_lds(
      (const __attribute__((address_space(1))) unsigned int*)g,
      (__attribute__((address_space(3))) unsigned int*)l, 16, 0, 0);
}

// inp[b,h] = bi[h] + sum_k x[b,k] * Wi[h,k]
__global__ __launch_bounds__(256) void prep_inp_k(const float* __restrict__ x,
    const float* __restrict__ Wi, const float* __restrict__ bi, float* __restrict__ inp) {
  int gid = blockIdx.x * 256 + threadIdx.x;   // 16384
  int b = gid >> 9, h = gid & 511;
  const float* xr = x + b * 512;
  const float* wr = Wi + h * 512;
  float acc = bi[h];
  #pragma unroll 4
  for (int k = 0; k < 512; k += 4) {
    float4 xv = *(const float4*)(xr + k);
    float4 wv = *(const float4*)(wr + k);
    acc += xv.x * wv.x + xv.y * wv.y + xv.z * wv.z + xv.w * wv.w;
  }
  inp[gid] = acc;
}

// W packed bf16 (hi only): region (TN 0..7, KS 0..15) = 256 n-rows x 32 k.
// 131072 chunks of 8 -> grid 512 x 256.
__global__ __launch_bounds__(256) void prep_w_pack_k(const float* __restrict__ w0,
    const float* __restrict__ w1, const float* __restrict__ w2, const float* __restrict__ w3,
    short* __restrict__ Whi) {
  int gid = blockIdx.x * 256 + threadIdx.x;
  if (gid >= 131072) return;
  int c = gid & 3, row = (gid >> 2) & 255, TK = gid >> 10;  // TK = TN*16+KS
  int TN = TK >> 4, KS = TK & 15;
  int n = TN * 256 + row;
  int g = n >> 9, h = n & 511;
  const float* w = (g == 0) ? w0 : (g == 1) ? w1 : (g == 2) ? w2 : w3;
  float f[8];
  *(float4*)&f[0] = *(const float4*)(w + (size_t)h * 512 + KS * 32 + c * 8);
  *(float4*)&f[4] = *(const float4*)(w + (size_t)h * 512 + KS * 32 + c * 8 + 4);
  short8v hv;
  #pragma unroll
  for (int i = 0; i < 8; ++i) hv[i] = (short)f2bf(f[i]);
  *(short8v*)(Whi + (size_t)gid * 8) = hv;
}

// ctx packed bf16: region (TM 0..255, KS 0..15) = 256 m-rows x 32 k.
__global__ __launch_bounds__(256) void prep_ctx_pack_k(const float* __restrict__ ctx,
    short* __restrict__ Chi) {
  int gid = blockIdx.x * 256 + threadIdx.x;   // 4194304 chunks of 8
  int c = gid & 3, row = (gid >> 2) & 255, TK = gid >> 10;  // TK = TM*16+KS
  int TM = TK >> 4, KS = TK & 15;
  size_t m = (size_t)TM * 256 + row;
  int k = KS * 32 + c * 8;
  float f[8];
  *(float4*)&f[0] = *(const float4*)(ctx + m * 512 + k);
  *(float4*)&f[4] = *(const float4*)(ctx + m * 512 + k + 4);
  short8v hv;
  #pragma unroll
  for (int i = 0; i < 8; ++i) hv[i] = (short)f2bf(f[i]);
  *(short8v*)(Chi + (size_t)gid * 8) = hv;
}

// Main: 256x256 tile, BK=32, 8 waves (2 wr x 4 wc), per-wave 128x64.
// Single-term bf16 MFMA; fused tanh/V epilogue -> att_approx.
template<bool PRESPLIT>
__global__ __launch_bounds__(512, 2) void gemm_att_k(
    const float* __restrict__ ctx, const short* __restrict__ Chi,
    const short* __restrict__ Whi,
    const float* __restrict__ inp,
    const float* __restrict__ bc0, const float* __restrict__ bc1,
    const float* __restrict__ bc2, const float* __restrict__ bc3,
    const float* __restrict__ V, float* __restrict__ att) {
  __shared__ __align__(16) short smem[2][2][8192];   // 64 KiB: [buf][A|B]
  __shared__ float sV[256], sPre[256];

  const int t = threadIdx.x;
  int d = blockIdx.x + (blockIdx.y << 3);
  int work = (d & 7) * 256 + (d >> 3);           // XCD-contiguous chunks
  int mt = work >> 3, nt = work & 7;
  int b = mt >> 3;
  int g = nt >> 1, h0 = (nt & 1) * 256;

  if (t < 256) {
    const float* bc = (g == 0) ? bc0 : (g == 1) ? bc1 : (g == 2) ? bc2 : bc3;
    sV[t] = V[h0 + t];
    sPre[t] = inp[b * 512 + h0 + t] + bc[h0 + t];
  }

  const int toff = t * 8;   // t*16 bytes
  auto stage = [&](int buf, int ks) {
    short* lb = &smem[buf][0][0];
    if (PRESPLIT) {
      const short* gA = Chi + (((size_t)mt * 16 + ks) << 13) + toff;
      gl_lds16(gA,        lb + toff);
      gl_lds16(gA + 4096, lb + toff + 4096);
    } else {
      int row = t >> 1, half = t & 1;
      const float* src = ctx + ((size_t)mt * 256 + row) * 512 + ks * 32 + half * 16;
      float f0[8], f1[8];
      *(float4*)&f0[0] = *(const float4*)(src);
      *(float4*)&f0[4] = *(const float4*)(src + 4);
      *(float4*)&f1[0] = *(const float4*)(src + 8);
      *(float4*)&f1[4] = *(const float4*)(src + 12);
      short8v h0v, h1v;
      #pragma unroll
      for (int i = 0; i < 8; ++i) { h0v[i] = (short)f2bf(f0[i]); h1v[i] = (short)f2bf(f1[i]); }
      int o = row * 32 + half * 16;
      *(short8v*)&smem[buf][0][o] = h0v;
      *(short8v*)&smem[buf][0][o + 8] = h1v;
    }
    const short* gB = Whi + (((size_t)nt * 16 + ks) << 13) + toff;
    gl_lds16(gB,        lb + 8192 + toff);
    gl_lds16(gB + 4096, lb + 8192 + toff + 4096);
  };

  f32x4 acc[8][4];
  #pragma unroll
  for (int i = 0; i < 8; ++i)
    #pragma unroll
    for (int j = 0; j < 4; ++j) acc[i][j] = (f32x4){0.f, 0.f, 0.f, 0.f};

  const int lane = t & 63, wid = t >> 6;
  const int wr = wid >> 2, wc = wid & 3;
  const int fr = lane & 15, fq = lane >> 4;

  stage(0, 0);
  __syncthreads();

  for (int ks = 0; ks < 16; ++ks) {
    int cur = ks & 1;
    if (ks + 1 < 16) stage(cur ^ 1, ks + 1);

    const short* sa = &smem[cur][0][0];
    bf16x8 ah[8], bh[4];
    #pragma unroll
    for (int mi = 0; mi < 8; ++mi)
      ah[mi] = *(const bf16x8*)(sa + (wr * 128 + mi * 16 + fr) * 32 + fq * 8);
    #pragma unroll
    for (int ni = 0; ni < 4; ++ni)
      bh[ni] = *(const bf16x8*)(sa + 8192 + (wc * 64 + ni * 16 + fr) * 32 + fq * 8);
    #pragma unroll
    for (int mi = 0; mi < 8; ++mi)
      #pragma unroll
      for (int ni = 0; ni < 4; ++ni)
        acc[mi][ni] = __builtin_amdgcn_mfma_f32_16x16x32_bf16(ah[mi], bh[ni], acc[mi][ni], 0, 0, 0);
    __syncthreads();
  }

  float vV[4], vP[4];
  #pragma unroll
  for (int ni = 0; ni < 4; ++ni) {
    int j = wc * 64 + ni * 16 + fr;
    vV[ni] = sV[j];
    vP[ni] = sPre[j];
  }
  size_t abase = (size_t)b * 8192 + (size_t)g * 2048;
  #pragma unroll
  for (int mi = 0; mi < 8; ++mi) {
    #pragma unroll
    for (int r = 0; r < 4; ++r) {
      float sum = 0.f;
      #pragma unroll
      for (int ni = 0; ni < 4; ++ni)
        sum += vV[ni] * tanh_fast(vP[ni] + acc[mi][ni][r]);
      sum += __shfl_xor(sum, 1, 64);
      sum += __shfl_xor(sum, 2, 64);
      sum += __shfl_xor(sum, 4, 64);
      sum += __shfl_xor(sum, 8, 64);
      if (fr == 0) {
        int s = (mt * 256 + wr * 128 + mi * 16 + fq * 4 + r) & 2047;
        atomicAdd(&att[abase + s], sum);
      }
    }
  }
}

// F1: per-batch approx max, softmax denominator, candidate collection, mask out
__global__ __launch_bounds__(256) void reduce_k(const float* __restrict__ att,
    const unsigned char* __restrict__ mask,
    float* __restrict__ den, float* __restrict__ maxa, int* __restrict__ cnt,
    int* __restrict__ cand_j, float* __restrict__ cand_a, float* __restrict__ out) {
  int b = blockIdx.x, t = threadIdx.x;
  __shared__ float sred[256];
  float bm = -1e30f;
  for (int j = t; j < 8192; j += 256) {
    if (mask[b * 2048 + (j & 2047)]) continue;
    float a = att[(size_t)b * 8192 + j];
    bm = fmaxf(bm, a);
  }
  sred[t] = bm;
  __syncthreads();
  for (int s2 = 128; s2 > 0; s2 >>= 1) {
    if (t < s2) sred[t] = fmaxf(sred[t], sred[t + s2]);
    __syncthreads();
  }
  float mx = sred[0];
  float Lref = 10.f * tanhf(mx);
  __syncthreads();
  float se = 0.f;
  for (int j = t; j < 8192; j += 256) {
    if (mask[b * 2048 + (j & 2047)]) continue;
    float a = att[(size_t)b * 8192 + j];
    se += expf(10.f * tanhf(a) - Lref);
    if (a >= mx - MARGIN) {
      int slot = atomicAdd(&cnt[b], 1);
      if (slot < NCAND) {
        cand_j[b * NCAND + slot] = j;
        cand_a[b * NCAND + slot] = a;
      }
    }
  }
  sred[t] = se;
  __syncthreads();
  for (int s2 = 128; s2 > 0; s2 >>= 1) {
    if (t < s2) sred[t] += sred[t + s2];
    __syncthreads();
  }
  if (t == 0) { den[b] = sred[0]; maxa[b] = mx; }
  for (int j = t; j < 2048; j += 256)
    out[64 + b * 2048 + j] = mask[b * 2048 + j] ? 1.0f : 0.0f;
}

// F2: exact fp32 rescore of candidate (b, slot)
__global__ __launch_bounds__(256) void rescore_k(const float* __restrict__ ctx,
    const float* __restrict__ Wc0, const float* __restrict__ Wc1,
    const float* __restrict__ Wc2, const float* __restrict__ Wc3,
    const float* __restrict__ bc0, const float* __restrict__ bc1,
    const float* __restrict__ bc2, const float* __restrict__ bc3,
    const float* __restrict__ inp, const float* __restrict__ V,
    const int* __restrict__ cnt, const int* __restrict__ cand_j,
    float* __restrict__ cand_e) {
  int slot = blockIdx.x, b = blockIdx.y, t = threadIdx.x;
  int n = min(cnt[b], NCAND);
  if (slot >= n) return;
  int j = cand_j[b * NCAND + slot];
  int g = j >> 11, s = j & 2047;
  const float* W  = (g == 0) ? Wc0 : (g == 1) ? Wc1 : (g == 2) ? Wc2 : Wc3;
  const float* bc = (g == 0) ? bc0 : (g == 1) ? bc1 : (g == 2) ? bc2 : bc3;
  __shared__ float sctx[512];
  __shared__ float sred[256];
  const float* cr = ctx + ((size_t)b * 2048 + s) * 512;
  sctx[t] = cr[t];
  sctx[t + 256] = cr[t + 256];
  __syncthreads();
  float total = 0.f;
  #pragma unroll
  for (int hh = 0; hh < 2; ++hh) {
    int h = t + hh * 256;
    const float* wr = W + (size_t)h * 512;
    float acc = 0.f;
    #pragma unroll 4
    for (int k = 0; k < 512; k += 4) {
      float4 wv = *(const float4*)(wr + k);
      acc += wv.x * sctx[k] + wv.y * sctx[k + 1] + wv.z * sctx[k + 2] + wv.w * sctx[k + 3];
    }
    total += V[h] * tanhf(inp[b * 512 + h] + bc[h] + acc);
  }
  sred[t] = total;
  __syncthreads();
  for (int s2 = 128; s2 > 0; s2 >>= 1) {
    if (t < s2) sred[t] += sred[t + s2];
    __syncthreads();
  }
  if (t == 0) cand_e[b * NCAND + slot] = sred[0];
}

// F3: exact argmax among candidates + corrected denominator -> indices, p
__global__ __launch_bounds__(64) void final_k(
    const float* __restrict__ den, const float* __restrict__ maxa,
    const int* __restrict__ cnt, const int* __restrict__ cand_j,
    const float* __restrict__ cand_a, const float* __restrict__ cand_e,
    float* __restrict__ out) {
  int b = blockIdx.x;
  if (threadIdx.x != 0) return;
  int n = min(cnt[b], NCAND);
  float Lref = 10.f * tanhf(maxa[b]);
  float d = den[b];
  float best = -1e30f;
  int bj = 0x7fffffff;
  for (int i = 0; i < n; ++i) {
    float e = cand_e[b * NCAND + i];
    int j = cand_j[b * NCAND + i];
    d += expf(10.f * tanhf(e) - Lref) - expf(10.f * tanhf(cand_a[b * NCAND + i]) - Lref);
    if (e > best || (e == best && j < bj)) { best = e; bj = j; }
  }
  out[b] = (float)bj;
  out[32 + b] = expf(10.f * tanhf(best) - Lref) / d;
}

extern "C" void kernel_launch(void* const* d_in, const int* in_sizes, int n_in,
                              void* d_out, int out_size, void* d_ws, size_t ws_size,
                              hipStream_t stream) {
  const float* x    = (const float*)d_in[0];
  const float* ctx  = (const float*)d_in[1];
  const unsigned char* mask = (const unsigned char*)d_in[2];
  const float* Wi   = (const float*)d_in[3];
  const float* bi   = (const float*)d_in[4];
  const float* Wc0  = (const float*)d_in[5];
  const float* bc0  = (const float*)d_in[6];
  const float* Wc1  = (const float*)d_in[7];
  const float* bc1  = (const float*)d_in[8];
  const float* Wc2  = (const float*)d_in[9];
  const float* bc2  = (const float*)d_in[10];
  const float* Wc3  = (const float*)d_in[11];
  const float* bc3  = (const float*)d_in[12];
  const float* V    = (const float*)d_in[13];
  float* out = (float*)d_out;

  float* inp    = (float*)d_ws;            // 16384
  float* att    = inp + 16384;             // 262144
  float* den    = att + 262144;            // 32
  float* maxa   = den + 32;                // 32
  int*   cnt    = (int*)(maxa + 32);       // 32
  int*   cand_j = cnt + 32;                // 1024
  float* cand_a = (float*)(cand_j + 1024); // 1024
  float* cand_e = cand_a + 1024;           // 1024
  short* Whi    = (short*)(cand_e + 1024); // 1048576 shorts
  short* Chi    = Whi + 1048576;           // 33554432 shorts
  size_t need = (size_t)((char*)(Chi + 33554432) - (char*)d_ws);
  bool presplit = ws_size >= need;

  hipMemsetAsync(att, 0, 262144 * sizeof(float), stream);
  hipMemsetAsync(cnt, 0, 32 * sizeof(int), stream);
  prep_inp_k<<<64, 256, 0, stream>>>(x, Wi, bi, inp);
  prep_w_pack_k<<<512, 256, 0, stream>>>(Wc0, Wc1, Wc2, Wc3, Whi);
  if (presplit) {
    prep_ctx_pack_k<<<16384, 256, 0, stream>>>(ctx, Chi);
    gemm_att_k<true><<<dim3(8, 256), 512, 0, stream>>>(ctx, Chi, Whi,
        inp, bc0, bc1, bc2, bc3, V, att);
  } else {
    gemm_att_k<false><<<dim3(8, 256), 512, 0, stream>>>(ctx, nullptr, Whi,
        inp, bc0, bc1, bc2, bc3, V, att);
  }
  reduce_k<<<32, 256, 0, stream>>>(att, mask, den, maxa, cnt, cand_j, cand_a, out);
  rescore_k<<<dim3(NCAND, 32), 256, 0, stream>>>(ctx, Wc0, Wc1, Wc2, Wc3,
      bc0, bc1, bc2, bc3, inp, V, cnt, cand_j, cand_e);
  final_k<<<32, 64, 0, stream>>>(den, maxa, cnt, cand_j, cand_a, cand_e, out);
}

// Round 5
// 320.798 us; speedup vs baseline: 2.0663x; 1.2135x over previous
//
#include <hip/hip_runtime.h>
#include <math.h>

typedef __bf16 bf16x8 __attribute__((ext_vector_type(8)));
typedef float f32x4 __attribute__((ext_vector_type(4)));
typedef short short8v __attribute__((ext_vector_type(8)));

#define MARGIN 0.01f
#define NCAND 32

__device__ __forceinline__ unsigned short f2bf(float f) {
  unsigned u = __float_as_uint(f);
  u += 0x7fffu + ((u >> 16) & 1u);
  return (unsigned short)(u >> 16);
}
__device__ __forceinline__ float tanh_fast(float x) {
  float e = __builtin_amdgcn_exp2f(x * 2.885390081777927f);
  return 1.f - 2.f * __builtin_amdgcn_rcpf(e + 1.f);
}
__device__ __forceinline__ void gl_lds16(const void* g, void* l) {
  __builtin_amdgcn_global_load_lds(
      (const __attribute__((address_space(1))) unsigned int*)g,
      (__attribute__((address_space(3))) unsigned int*)l, 16, 0, 0);
}

// inp[b,h] = bi[h] + sum_k x[b,k] * Wi[h,k]
__global__ __launch_bounds__(256) void prep_inp_k(const float* __restrict__ x,
    const float* __restrict__ Wi, const float* __restrict__ bi, float* __restrict__ inp) {
  int gid = blockIdx.x * 256 + threadIdx.x;   // 16384
  int b = gid >> 9, h = gid & 511;
  const float* xr = x + b * 512;
  const float* wr = Wi + h * 512;
  float acc = bi[h];
  #pragma unroll 4
  for (int k = 0; k < 512; k += 4) {
    float4 xv = *(const float4*)(xr + k);
    float4 wv = *(const float4*)(wr + k);
    acc += xv.x * wv.x + xv.y * wv.y + xv.z * wv.z + xv.w * wv.w;
  }
  inp[gid] = acc;
}

// Packed layout (A and B identical): region (tile, KS) = 256 rows x 32 k shorts.
// Within a row (4 chunks of 8 shorts = 16B), chunk at POSITION c holds DATA
// k-chunk c ^ ((row>>1)&3)  -> bank-conflict-free b128 fragment reads (T2),
// while global_load_lds stays linear (rule #21: pre-swizzled source).
__global__ __launch_bounds__(256) void prep_w_pack_k(const float* __restrict__ w0,
    const float* __restrict__ w1, const float* __restrict__ w2, const float* __restrict__ w3,
    short* __restrict__ Whi) {
  int gid = blockIdx.x * 256 + threadIdx.x;
  if (gid >= 131072) return;                  // 2048*512/8 chunks
  int c = gid & 3, row = (gid >> 2) & 255, TK = gid >> 10;  // TK = TN*16+KS
  int TN = TK >> 4, KS = TK & 15;
  int n = TN * 256 + row;
  int g = n >> 9, h = n & 511;
  const float* w = (g == 0) ? w0 : (g == 1) ? w1 : (g == 2) ? w2 : w3;
  int csrc = c ^ ((row >> 1) & 3);            // swizzle: fetch permuted source
  const float* src = w + (size_t)h * 512 + KS * 32 + csrc * 8;
  float f[8];
  *(float4*)&f[0] = *(const float4*)(src);
  *(float4*)&f[4] = *(const float4*)(src + 4);
  short8v hv;
  #pragma unroll
  for (int i = 0; i < 8; ++i) hv[i] = (short)f2bf(f[i]);
  *(short8v*)(Whi + (size_t)gid * 8) = hv;
}

__global__ __launch_bounds__(256) void prep_ctx_pack_k(const float* __restrict__ ctx,
    short* __restrict__ Chi) {
  int gid = blockIdx.x * 256 + threadIdx.x;   // 4194304 chunks of 8
  int c = gid & 3, row = (gid >> 2) & 255, TK = gid >> 10;  // TK = TM*16+KS
  int TM = TK >> 4, KS = TK & 15;
  size_t m = (size_t)TM * 256 + row;
  int csrc = c ^ ((row >> 1) & 3);
  int k = KS * 32 + csrc * 8;
  float f[8];
  *(float4*)&f[0] = *(const float4*)(ctx + m * 512 + k);
  *(float4*)&f[4] = *(const float4*)(ctx + m * 512 + k + 4);
  short8v hv;
  #pragma unroll
  for (int i = 0; i < 8; ++i) hv[i] = (short)f2bf(f[i]);
  *(short8v*)(Chi + (size_t)gid * 8) = hv;
}

// Main: 256x256 tile, BK=32, 8 waves (2 wr x 4 wc), per-wave 128x64.
// bf16 MFMA, T2-swizzled LDS, fused tanh/V epilogue -> att_approx.
template<bool PRESPLIT>
__global__ __launch_bounds__(512, 2) void gemm_att_k(
    const float* __restrict__ ctx, const short* __restrict__ Chi,
    const short* __restrict__ Whi,
    const float* __restrict__ inp,
    const float* __restrict__ bc0, const float* __restrict__ bc1,
    const float* __restrict__ bc2, const float* __restrict__ bc3,
    const float* __restrict__ V, float* __restrict__ att) {
  __shared__ __align__(16) short smem[2][2][8192];   // 64 KiB: [buf][A|B]
  __shared__ float sV[256], sPre[256];

  const int t = threadIdx.x;
  int d = blockIdx.x + (blockIdx.y << 3);
  int work = (d & 7) * 256 + (d >> 3);           // XCD-contiguous chunks
  int mt = work >> 3, nt = work & 7;
  int b = mt >> 3;
  int g = nt >> 1, h0 = (nt & 1) * 256;

  if (t < 256) {
    const float* bc = (g == 0) ? bc0 : (g == 1) ? bc1 : (g == 2) ? bc2 : bc3;
    sV[t] = V[h0 + t];
    sPre[t] = inp[b * 512 + h0 + t] + bc[h0 + t];
  }

  const int toff = t * 8;   // t*16 bytes
  auto stage = [&](int buf, int ks) {
    short* lb = &smem[buf][0][0];
    if (PRESPLIT) {
      const short* gA = Chi + (((size_t)mt * 16 + ks) << 13) + toff;
      gl_lds16(gA,        lb + toff);
      gl_lds16(gA + 4096, lb + toff + 4096);
    } else {
      int row = t >> 1, half = t & 1;
      const float* src = ctx + ((size_t)mt * 256 + row) * 512 + ks * 32 + half * 16;
      float f0[8], f1[8];
      *(float4*)&f0[0] = *(const float4*)(src);
      *(float4*)&f0[4] = *(const float4*)(src + 4);
      *(float4*)&f1[0] = *(const float4*)(src + 8);
      *(float4*)&f1[4] = *(const float4*)(src + 12);
      short8v h0v, h1v;
      #pragma unroll
      for (int i = 0; i < 8; ++i) { h0v[i] = (short)f2bf(f0[i]); h1v[i] = (short)f2bf(f1[i]); }
      int s = (row >> 1) & 3;
      int p0 = (half * 2) ^ s, p1 = (half * 2 + 1) ^ s;   // swizzled chunk slots
      *(short8v*)&smem[buf][0][row * 32 + p0 * 8] = h0v;
      *(short8v*)&smem[buf][0][row * 32 + p1 * 8] = h1v;
    }
    const short* gB = Whi + (((size_t)nt * 16 + ks) << 13) + toff;
    gl_lds16(gB,        lb + 8192 + toff);
    gl_lds16(gB + 4096, lb + 8192 + toff + 4096);
  };

  f32x4 acc[8][4];
  #pragma unroll
  for (int i = 0; i < 8; ++i)
    #pragma unroll
    for (int j = 0; j < 4; ++j) acc[i][j] = (f32x4){0.f, 0.f, 0.f, 0.f};

  const int lane = t & 63, wid = t >> 6;
  const int wr = wid >> 2, wc = wid & 3;
  const int fr = lane & 15, fq = lane >> 4;
  const int csw = fq ^ ((fr >> 1) & 3);          // swizzled read chunk (per-thread const)

  stage(0, 0);
  __syncthreads();

  for (int ks = 0; ks < 16; ++ks) {
    int cur = ks & 1;
    if (ks + 1 < 16) stage(cur ^ 1, ks + 1);

    const short* sa = &smem[cur][0][0];
    bf16x8 ah[8], bh[4];
    #pragma unroll
    for (int mi = 0; mi < 8; ++mi)
      ah[mi] = *(const bf16x8*)(sa + (wr * 128 + mi * 16 + fr) * 32 + csw * 8);
    #pragma unroll
    for (int ni = 0; ni < 4; ++ni)
      bh[ni] = *(const bf16x8*)(sa + 8192 + (wc * 64 + ni * 16 + fr) * 32 + csw * 8);
    #pragma unroll
    for (int mi = 0; mi < 8; ++mi)
      #pragma unroll
      for (int ni = 0; ni < 4; ++ni)
        acc[mi][ni] = __builtin_amdgcn_mfma_f32_16x16x32_bf16(ah[mi], bh[ni], acc[mi][ni], 0, 0, 0);
    __syncthreads();
  }

  float vV[4], vP[4];
  #pragma unroll
  for (int ni = 0; ni < 4; ++ni) {
    int j = wc * 64 + ni * 16 + fr;
    vV[ni] = sV[j];
    vP[ni] = sPre[j];
  }
  size_t abase = (size_t)b * 8192 + (size_t)g * 2048;
  #pragma unroll
  for (int mi = 0; mi < 8; ++mi) {
    #pragma unroll
    for (int r = 0; r < 4; ++r) {
      float sum = 0.f;
      #pragma unroll
      for (int ni = 0; ni < 4; ++ni)
        sum += vV[ni] * tanh_fast(vP[ni] + acc[mi][ni][r]);
      sum += __shfl_xor(sum, 1, 64);
      sum += __shfl_xor(sum, 2, 64);
      sum += __shfl_xor(sum, 4, 64);
      sum += __shfl_xor(sum, 8, 64);
      if (fr == 0) {
        int s = (mt * 256 + wr * 128 + mi * 16 + fq * 4 + r) & 2047;
        atomicAdd(&att[abase + s], sum);
      }
    }
  }
}

// Fused tail: per-batch max + denom + candidates (F1), exact fp32 rescore (F2),
// final argmax + corrected p (F3), mask passthrough. One block per batch.
__global__ __launch_bounds__(256) void tail_k(const float* __restrict__ att,
    const unsigned char* __restrict__ mask, const float* __restrict__ ctx,
    const float* __restrict__ Wc0, const float* __restrict__ Wc1,
    const float* __restrict__ Wc2, const float* __restrict__ Wc3,
    const float* __restrict__ bc0, const float* __restrict__ bc1,
    const float* __restrict__ bc2, const float* __restrict__ bc3,
    const float* __restrict__ inp, const float* __restrict__ V,
    float* __restrict__ out) {
  int b = blockIdx.x, t = threadIdx.x;
  __shared__ float sred[256];
  __shared__ float sctx[512];
  __shared__ int scnt;
  __shared__ int scand_j[NCAND];
  __shared__ float scand_a[NCAND];
  __shared__ float sexact[NCAND];

  if (t == 0) scnt = 0;
  // pass 1: approx max
  float bm = -1e30f;
  for (int j = t; j < 8192; j += 256) {
    if (mask[b * 2048 + (j & 2047)]) continue;
    bm = fmaxf(bm, att[(size_t)b * 8192 + j]);
  }
  sred[t] = bm;
  __syncthreads();
  for (int s2 = 128; s2 > 0; s2 >>= 1) {
    if (t < s2) sred[t] = fmaxf(sred[t], sred[t + s2]);
    __syncthreads();
  }
  float mx = sred[0];
  float Lref = 10.f * tanhf(mx);
  __syncthreads();
  // pass 2: denom + candidate collection
  float se = 0.f;
  for (int j = t; j < 8192; j += 256) {
    if (mask[b * 2048 + (j & 2047)]) continue;
    float a = att[(size_t)b * 8192 + j];
    se += expf(10.f * tanhf(a) - Lref);
    if (a >= mx - MARGIN) {
      int slot = atomicAdd(&scnt, 1);
      if (slot < NCAND) { scand_j[slot] = j; scand_a[slot] = a; }
    }
  }
  sred[t] = se;
  __syncthreads();
  for (int s2 = 128; s2 > 0; s2 >>= 1) {
    if (t < s2) sred[t] += sred[t + s2];
    __syncthreads();
  }
  float den = sred[0];
  int n = min(scnt, NCAND);
  // mask passthrough
  for (int j = t; j < 2048; j += 256)
    out[64 + b * 2048 + j] = mask[b * 2048 + j] ? 1.0f : 0.0f;
  // exact rescore of each candidate (block-cooperative)
  for (int i = 0; i < n; ++i) {
    int jj = scand_j[i];
    int g = jj >> 11, s = jj & 2047;
    const float* W  = (g == 0) ? Wc0 : (g == 1) ? Wc1 : (g == 2) ? Wc2 : Wc3;
    const float* bc = (g == 0) ? bc0 : (g == 1) ? bc1 : (g == 2) ? bc2 : bc3;
    const float* cr = ctx + ((size_t)b * 2048 + s) * 512;
    __syncthreads();
    sctx[t] = cr[t];
    sctx[t + 256] = cr[t + 256];
    __syncthreads();
    float total = 0.f;
    #pragma unroll
    for (int hh = 0; hh < 2; ++hh) {
      int h = t + hh * 256;
      const float* wr = W + (size_t)h * 512;
      float acc = 0.f;
      #pragma unroll 4
      for (int k = 0; k < 512; k += 4) {
        float4 wv = *(const float4*)(wr + k);
        acc += wv.x * sctx[k] + wv.y * sctx[k + 1] + wv.z * sctx[k + 2] + wv.w * sctx[k + 3];
      }
      total += V[h] * tanhf(inp[b * 512 + h] + bc[h] + acc);
    }
    sred[t] = total;
    __syncthreads();
    for (int s2 = 128; s2 > 0; s2 >>= 1) {
      if (t < s2) sred[t] += sred[t + s2];
      __syncthreads();
    }
    if (t == 0) sexact[i] = sred[0];
  }
  __syncthreads();
  if (t == 0) {
    float d = den, best = -1e30f;
    int bj = 0x7fffffff;
    for (int i = 0; i < n; ++i) {
      float e = sexact[i];
      int j = scand_j[i];
      d += expf(10.f * tanhf(e) - Lref) - expf(10.f * tanhf(scand_a[i]) - Lref);
      if (e > best || (e == best && j < bj)) { best = e; bj = j; }
    }
    out[b] = (float)bj;
    out[32 + b] = expf(10.f * tanhf(best) - Lref) / d;
  }
}

extern "C" void kernel_launch(void* const* d_in, const int* in_sizes, int n_in,
                              void* d_out, int out_size, void* d_ws, size_t ws_size,
                              hipStream_t stream) {
  const float* x    = (const float*)d_in[0];
  const float* ctx  = (const float*)d_in[1];
  const unsigned char* mask = (const unsigned char*)d_in[2];
  const float* Wi   = (const float*)d_in[3];
  const float* bi   = (const float*)d_in[4];
  const float* Wc0  = (const float*)d_in[5];
  const float* bc0  = (const float*)d_in[6];
  const float* Wc1  = (const float*)d_in[7];
  const float* bc1  = (const float*)d_in[8];
  const float* Wc2  = (const float*)d_in[9];
  const float* bc2  = (const float*)d_in[10];
  const float* Wc3  = (const float*)d_in[11];
  const float* bc3  = (const float*)d_in[12];
  const float* V    = (const float*)d_in[13];
  float* out = (float*)d_out;

  float* inp    = (float*)d_ws;            // 16384
  float* att    = inp + 16384;             // 262144
  short* Whi    = (short*)(att + 262144);  // 1048576 shorts
  short* Chi    = Whi + 1048576;           // 33554432 shorts
  size_t need = (size_t)((char*)(Chi + 33554432) - (char*)d_ws);
  bool presplit = ws_size >= need;

  hipMemsetAsync(att, 0, 262144 * sizeof(float), stream);
  prep_inp_k<<<64, 256, 0, stream>>>(x, Wi, bi, inp);
  prep_w_pack_k<<<512, 256, 0, stream>>>(Wc0, Wc1, Wc2, Wc3, Whi);
  if (presplit) {
    prep_ctx_pack_k<<<16384, 256, 0, stream>>>(ctx, Chi);
    gemm_att_k<true><<<dim3(8, 256), 512, 0, stream>>>(ctx, Chi, Whi,
        inp, bc0, bc1, bc2, bc3, V, att);
  } else {
    gemm_att_k<false><<<dim3(8, 256), 512, 0, stream>>>(ctx, nullptr, Whi,
        inp, bc0, bc1, bc2, bc3, V, att);
  }
  tail_k<<<32, 256, 0, stream>>>(att, mask, ctx, Wc0, Wc1, Wc2, Wc3,
      bc0, bc1, bc2, bc3, inp, V, out);
}